// Round 5
// baseline (433.792 us; speedup 1.0000x reference)
//
#include <hip/hip_runtime.h>

#define TT 512
#define BB 64
#define DD 768
#define NEG (-1e30f)

__device__ __forceinline__ float fmax3(float a, float b, float c) {
    return fmaxf(fmaxf(a, b), c);
}
__device__ __forceinline__ int imin3(int a, int b, int c) {
    return min(min(a, b), c);
}
__device__ __forceinline__ float rl(float x, int i) {
    return __int_as_float(__builtin_amdgcn_readlane(__float_as_int(x), i));
}
__device__ __forceinline__ float dot4(float4 a, float4 b) {
    return a.x * b.x + a.y * b.y + a.z * b.z + a.w * b.w;
}

// ---------------------------------------------------------------------------
// Kernel 1: fused skinny GEMM.
// 8 lanes per row, 2 rows per thread (r, r+32) sharing wT ds_reads.
// Double-buffered batches of 4 float4 per row: live set ~100 VGPR (no spill),
// up to 8 outstanding global loads per wave. Grid 512 x 256 = 64 rows/block.
// ---------------------------------------------------------------------------
__global__ __launch_bounds__(256, 4) void gemm_kernel(
    const float* __restrict__ x,
    const float* __restrict__ W1, const float* __restrict__ b1,
    const float* __restrict__ W2, const float* __restrict__ b2,
    float* __restrict__ o1, float* __restrict__ o2)
{
    __shared__ float wT[11][DD];
    const int tid = threadIdx.x;
    // conflict-free staging: consecutive lanes write consecutive d
    for (int i = tid; i < DD * 2; i += 256) { int cI = i >> 9 ; int d = i & 511; // DD*2=1536: cI=i/768
        (void)cI; }
    for (int i = tid; i < DD * 2; i += 256) { int cI = i / DD, d = i - cI * DD; wT[cI][d] = W1[d * 2 + cI]; }
    for (int i = tid; i < DD * 9; i += 256) { int cI = i / DD, d = i - cI * DD; wT[2 + cI][d] = W2[d * 9 + cI]; }
    __syncthreads();

    const int slot = tid >> 3;          // 0..31
    const int c    = tid & 7;           // 8 lanes per row
    const int r0   = blockIdx.x * 64 + slot;
    const int r1   = r0 + 32;
    const float4* x0 = reinterpret_cast<const float4*>(x + (size_t)r0 * DD);
    const float4* x1 = reinterpret_cast<const float4*>(x + (size_t)r1 * DD);

    float acc0[11], acc1[11];
#pragma unroll
    for (int m = 0; m < 11; ++m) { acc0[m] = 0.f; acc1[m] = 0.f; }

    float4 A0[4], A1[4], B0[4], B1[4];
#pragma unroll
    for (int k = 0; k < 4; ++k) { A0[k] = x0[k * 8 + c]; A1[k] = x1[k * 8 + c]; }

#pragma unroll
    for (int bt = 0; bt < 6; ++bt) {
        if (bt < 5) {
#pragma unroll
            for (int k = 0; k < 4; ++k) {
                B0[k] = x0[((bt + 1) * 4 + k) * 8 + c];
                B1[k] = x1[((bt + 1) * 4 + k) * 8 + c];
            }
        }
#pragma unroll
        for (int k = 0; k < 4; ++k) {
            const int d = ((bt * 4 + k) * 8 + c) * 4;
#pragma unroll
            for (int m = 0; m < 11; ++m) {
                float4 wv = *reinterpret_cast<const float4*>(&wT[m][d]);
                acc0[m] += dot4(A0[k], wv);
                acc1[m] += dot4(A1[k], wv);
            }
        }
        if (bt < 5) {
#pragma unroll
            for (int k = 0; k < 4; ++k) { A0[k] = B0[k]; A1[k] = B1[k]; }
        }
    }

    // butterfly reduce over the 8 lanes of the row group
#pragma unroll
    for (int m = 0; m < 11; ++m) {
        acc0[m] += __shfl_xor(acc0[m], 1);
        acc0[m] += __shfl_xor(acc0[m], 2);
        acc0[m] += __shfl_xor(acc0[m], 4);
        acc1[m] += __shfl_xor(acc1[m], 1);
        acc1[m] += __shfl_xor(acc1[m], 2);
        acc1[m] += __shfl_xor(acc1[m], 4);
    }
    if (c < 2) { o1[r0 * 2 + c] = acc0[c] + b1[c]; o1[r1 * 2 + c] = acc1[c] + b1[c]; }
    else       { o2[r0 * 9 + (c - 2)] = acc0[c] + b2[c - 2]; o2[r1 * 9 + (c - 2)] = acc1[c] + b2[c - 2]; }
    if (c < 3) { o2[r0 * 9 + (c + 6)] = acc0[c + 8] + b2[c + 6]; o2[r1 * 9 + (c + 6)] = acc1[c + 8] + b2[c + 6]; }
}

// ---------------------------------------------------------------------------
// Kernel 2: unified CRF kernel, grid = 320 blocks x 256 threads.
//  blocks 0..63  : per-seq exact Viterbi (both CRFs) + backtrace + tags +
//                  accuracy counts + unary/binary score sums.
//  blocks 64..319: (b, chunk) lse chunk transfer matrices (4 x 128 steps).
// ---------------------------------------------------------------------------
__global__ __launch_bounds__(256) void crf_kernel(
    const float* __restrict__ o1, const float* __restrict__ o2,
    const int* __restrict__ label, const int* __restrict__ seqlen,
    const float* __restrict__ trans1, const float* __restrict__ trans2,
    float* __restrict__ dout,
    float* __restrict__ M1, float* __restrict__ M2,
    float* __restrict__ scores, float* __restrict__ counts)
{
    __shared__ float s_l2[TT][9];
    __shared__ float s_l1[TT][2];
    __shared__ int   s_lab[TT];
    __shared__ float s_tr2[81];
    __shared__ float s_tr1[4];
    __shared__ unsigned char s_bp2[TT][12];   // cols 9..11 = dump for idle lanes
    __shared__ unsigned char s_bp1[TT][2];
    __shared__ unsigned char s_path2[16][9][36];
    __shared__ unsigned char s_path1[16][2][36];
    __shared__ unsigned char s_sel2[16], s_sel1[16];
    __shared__ float s_part[2][4];
    __shared__ int s_last2, s_last1;
    __shared__ int s_cnt[4][3];

    const int tid  = threadIdx.x;
    const int wave = tid >> 6, lane = tid & 63;

    if (blockIdx.x >= 64) {
        // ================= lse chunk-matrix block =================
        const int bc  = blockIdx.x - 64;
        const int b   = bc >> 2, cch = bc & 3;
        const int sl  = seqlen[b];
        const int t0  = cch * 128 + 1;
        const int cap = (cch < 3) ? 128 : 127;
        int n = sl - t0; n = n < 0 ? 0 : (n > cap ? cap : n);

        for (int i = tid; i < cap * 9; i += 256) {
            int t = i / 9, k = i - t * 9;
            s_l2[t][k] = o2[((size_t)b * TT + t0 + t) * 9 + k];
        }
        for (int i = tid; i < cap * 2; i += 256) {
            int t = i >> 1, k = i & 1;
            s_l1[t][k] = o1[((size_t)b * TT + t0 + t) * 2 + k];
        }
        if (tid < 81) s_tr2[tid] = trans2[tid];
        if (tid >= 128 && tid < 132) s_tr1[tid - 128] = trans1[tid - 128];
        __syncthreads();

        if (wave < 2) {
            int L, i_row, jj, base2; bool active;
            if (wave == 0) {
                if (lane < 63) { active = true;  L = 9; i_row = lane / 9; jj = lane - i_row * 9; base2 = i_row * 9; }
                else           { active = false; L = 9; i_row = 0; jj = 0; base2 = 54; }
            } else {
                if (lane < 18)      { active = true;  L = 9; i_row = 7 + lane / 9; jj = lane % 9; base2 = (lane / 9) * 9; }
                else if (lane < 22) { active = true;  L = 2; i_row = (lane - 18) >> 1; jj = (lane - 18) & 1; base2 = 18 + ((lane - 18) & ~1); }
                else                { active = false; L = 2; i_row = 0; jj = 0; base2 = 18; }
            }

            float tcol[9], row[9];
#pragma unroll
            for (int k = 0; k < 9; ++k) {
                tcol[k] = (k < L) ? ((L == 9) ? s_tr2[k * 9 + jj] : s_tr1[k * 2 + jj]) : NEG;
                row[k]  = (k < L && k == i_row) ? 0.f : NEG;
            }
            const float* lp = (L == 9) ? &s_l2[0][jj] : &s_l1[0][jj];
            const int lstride = L;

            for (int tt = 0; tt < n; ++tt) {
                float l = lp[tt * lstride];
                float v[9];
#pragma unroll
                for (int k = 0; k < 9; ++k) v[k] = row[k] + tcol[k];
                float m = fmax3(fmax3(v[0], v[1], v[2]), fmax3(v[3], v[4], v[5]), fmax3(v[6], v[7], v[8]));
                float s = 0.f;
#pragma unroll
                for (int k = 0; k < 9; ++k) s += __expf(v[k] - m);
                float nv = m + __logf(s) + l;
#pragma unroll
                for (int k = 0; k < 9; ++k) {
                    float sv = __shfl(nv, base2 + (k < L ? k : 0));
                    row[k] = (k < L) ? sv : NEG;
                }
            }
            if (active) {
                if (L == 9) M2[((size_t)(b * 4 + cch)) * 81 + i_row * 9 + jj] = row[jj];
                else        M1[((size_t)(b * 4 + cch)) * 4  + i_row * 2 + jj] = row[jj];
            }
        }
        return;
    }

    // ================= per-sequence Viterbi block =================
    const int b  = blockIdx.x;
    const int sl = seqlen[b];

    // phase 0: vectorized staging + identity bp prefill
    {
        const float4* src = (const float4*)(o2 + (size_t)b * TT * 9);
        float4* dst = (float4*)&s_l2[0][0];
        for (int i = tid; i < TT * 9 / 4; i += 256) dst[i] = src[i];
    }
    {
        const float4* src = (const float4*)(o1 + (size_t)b * TT * 2);
        float4* dst = (float4*)&s_l1[0][0];
        for (int i = tid; i < TT * 2 / 4; i += 256) dst[i] = src[i];
    }
    {
        const int4* src = (const int4*)(label + (size_t)b * TT);
        int4* dst = (int4*)s_lab;
        for (int i = tid; i < TT / 4; i += 256) dst[i] = src[i];
    }
    if (tid < 81) s_tr2[tid] = trans2[tid];
    if (tid >= 96 && tid < 100) s_tr1[tid - 96] = trans1[tid - 96];
    for (int i = tid; i < TT * 12; i += 256) {
        int c = i % 12;
        ((unsigned char*)s_bp2)[i] = (unsigned char)(c < 9 ? c : 0);
    }
    for (int i = tid; i < TT * 2; i += 256) ((unsigned char*)s_bp1)[i] = (unsigned char)(i & 1);
    __syncthreads();

    // phase 1: forward scans + score sums
    if (wave == 0) {
        const int j  = (lane < 9) ? lane : 0;
        const int jw = (lane < 9) ? lane : 9;
        float tc0 = s_tr2[0 * 9 + j], tc1 = s_tr2[1 * 9 + j], tc2 = s_tr2[2 * 9 + j];
        float tc3 = s_tr2[3 * 9 + j], tc4 = s_tr2[4 * 9 + j], tc5 = s_tr2[5 * 9 + j];
        float tc6 = s_tr2[6 * 9 + j], tc7 = s_tr2[7 * 9 + j], tc8 = s_tr2[8 * 9 + j];
        float a0 = s_l2[0][0], a1 = s_l2[0][1], a2 = s_l2[0][2], a3 = s_l2[0][3];
        float a4 = s_l2[0][4], a5 = s_l2[0][5], a6 = s_l2[0][6], a7 = s_l2[0][7], a8 = s_l2[0][8];
        float lcur = s_l2[1][j];
        float lnext = s_l2[2][j];
        for (int t = 1; t < sl; ++t) {
            int tn = t + 2; tn = tn > 511 ? 511 : tn;
            float lnew = s_l2[tn][j];          // issued early, used 2 iters later
            float v0 = a0 + tc0, v1 = a1 + tc1, v2 = a2 + tc2;
            float v3 = a3 + tc3, v4 = a4 + tc4, v5 = a5 + tc5;
            float v6 = a6 + tc6, v7 = a7 + tc7, v8 = a8 + tc8;
            float m = fmax3(fmax3(v0, v1, v2), fmax3(v3, v4, v5), fmax3(v6, v7, v8));
            float nj = m + lcur;
            float n0 = rl(nj, 0), n1 = rl(nj, 1), n2 = rl(nj, 2);
            float n3 = rl(nj, 3), n4 = rl(nj, 4), n5 = rl(nj, 5);
            float n6 = rl(nj, 6), n7 = rl(nj, 7), n8 = rl(nj, 8);
            int c0 = (v0 == m) ? 0 : 15, c1 = (v1 == m) ? 1 : 15, c2 = (v2 == m) ? 2 : 15;
            int c3 = (v3 == m) ? 3 : 15, c4 = (v4 == m) ? 4 : 15, c5 = (v5 == m) ? 5 : 15;
            int c6 = (v6 == m) ? 6 : 15, c7 = (v7 == m) ? 7 : 15, c8 = (v8 == m) ? 8 : 15;
            int bi = imin3(imin3(c0, c1, c2), imin3(c3, c4, c5), imin3(c6, c7, c8));
            s_bp2[t][jw] = (unsigned char)bi;
            a0 = n0; a1 = n1; a2 = n2; a3 = n3; a4 = n4; a5 = n5; a6 = n6; a7 = n7; a8 = n8;
            lcur = lnext; lnext = lnew;
        }
        if (lane == 0) {
            float m = fmax3(fmax3(a0, a1, a2), fmax3(a3, a4, a5), fmax3(a6, a7, a8));
            int c0 = (a0 == m) ? 0 : 15, c1 = (a1 == m) ? 1 : 15, c2 = (a2 == m) ? 2 : 15;
            int c3 = (a3 == m) ? 3 : 15, c4 = (a4 == m) ? 4 : 15, c5 = (a5 == m) ? 5 : 15;
            int c6 = (a6 == m) ? 6 : 15, c7 = (a7 == m) ? 7 : 15, c8 = (a8 == m) ? 8 : 15;
            s_last2 = imin3(imin3(c0, c1, c2), imin3(c3, c4, c5), imin3(c6, c7, c8));
        }
    } else if (wave == 1) {
        if (lane == 0) {
            const float t00 = s_tr1[0], t01 = s_tr1[1], t10 = s_tr1[2], t11 = s_tr1[3];
            float a0v = s_l1[0][0], a1v = s_l1[0][1];
            float2 lc = *(const float2*)&s_l1[1][0];
            float2 ln = *(const float2*)&s_l1[2][0];
            for (int t = 1; t < sl; ++t) {
                int tn = t + 2; tn = tn > 511 ? 511 : tn;
                float2 lw = *(const float2*)&s_l1[tn][0];
                float x0 = a0v + t00, y0 = a1v + t10;
                int bp0 = (y0 > x0) ? 1 : 0;
                float n0 = fmaxf(x0, y0) + lc.x;
                float x1 = a0v + t01, y1 = a1v + t11;
                int bp1v = (y1 > x1) ? 1 : 0;
                float n1 = fmaxf(x1, y1) + lc.y;
                *(unsigned short*)&s_bp1[t][0] = (unsigned short)(bp0 | (bp1v << 8));
                a0v = n0; a1v = n1; lc = ln; ln = lw;
            }
            s_last1 = (a1v > a0v) ? 1 : 0;
        }
    } else {
        const int t0i = tid - 128;
        float u1 = 0.f, bs1 = 0.f, u2 = 0.f, bs2 = 0.f;
        for (int t = t0i; t < sl; t += 128) {
            int lb = s_lab[t]; int lb1 = lb > 0 ? 1 : 0;
            u1 += s_l1[t][lb1];
            u2 += s_l2[t][lb];
            if (t >= 1) {
                int lp = s_lab[t - 1]; int lp1 = lp > 0 ? 1 : 0;
                bs1 += s_tr1[lp1 * 2 + lb1];
                bs2 += s_tr2[lp * 9 + lb];
            }
        }
        for (int off = 32; off; off >>= 1) {
            u1 += __shfl_down(u1, off); bs1 += __shfl_down(bs1, off);
            u2 += __shfl_down(u2, off); bs2 += __shfl_down(bs2, off);
        }
        if (lane == 0) {
            s_part[wave - 2][0] = u1; s_part[wave - 2][1] = bs1;
            s_part[wave - 2][2] = u2; s_part[wave - 2][3] = bs2;
        }
    }
    __syncthreads();

    // phase 2: chunk-parallel backtraces (16 chunks x 32 steps, exact)
    if (tid < 144) {
        int cch = tid / 9, e = tid - cch * 9;
        int pe = (cch < 15) ? (cch + 1) * 32 : 511;
        int tag = e;
        for (int t = pe; t > cch * 32; --t) {
            tag = s_bp2[t][tag];
            s_path2[cch][e][t - 1 - cch * 32] = (unsigned char)tag;
        }
    } else if (tid >= 160 && tid < 192) {
        int k = tid - 160, cch = k >> 1, e = k & 1;
        int pe = (cch < 15) ? (cch + 1) * 32 : 511;
        int tag = e;
        for (int t = pe; t > cch * 32; --t) {
            tag = s_bp1[t][tag];
            s_path1[cch][e][t - 1 - cch * 32] = (unsigned char)tag;
        }
    } else if (tid >= 224 && tid < 228) {
        int k = tid - 224;
        scores[b * 4 + k] = s_part[0][k] + s_part[1][k];
    }
    __syncthreads();

    // phase 3: boundary resolve
    if (tid == 0) {
        int cur = s_last2;
        for (int c = 15; c >= 0; --c) { s_sel2[c] = (unsigned char)cur; cur = s_path2[c][cur][0]; }
    } else if (tid == 1) {
        int cur = s_last1;
        for (int c = 15; c >= 0; --c) { s_sel1[c] = (unsigned char)cur; cur = s_path1[c][cur][0]; }
    }
    __syncthreads();

    // phase 4: assemble tags + accuracy counts
    {
        int c1 = 0, c2 = 0, cc = 0;
        for (int p = tid; p < TT; p += 256) {
            int ch = p >> 5;
            int v2 = (p == 511) ? s_last2 : (int)s_path2[ch][s_sel2[ch]][p & 31];
            int v1 = (p == 511) ? s_last1 : (int)s_path1[ch][s_sel1[ch]][p & 31];
            int comb = (v1 == 0) ? 0 : v2;
            dout[(size_t)b * TT + p] = (float)comb;
            if (p < sl) {
                int lb = s_lab[p]; int lb1 = lb > 0 ? 1 : 0;
                c1 += (v1 == lb1); c2 += (v2 == lb); cc += (comb == lb);
            }
        }
        for (int off = 32; off; off >>= 1) {
            c1 += __shfl_down(c1, off); c2 += __shfl_down(c2, off); cc += __shfl_down(cc, off);
        }
        if (lane == 0) { s_cnt[wave][0] = c1; s_cnt[wave][1] = c2; s_cnt[wave][2] = cc; }
    }
    __syncthreads();
    if (tid == 0) {
        counts[b * 3 + 0] = (float)(s_cnt[0][0] + s_cnt[1][0] + s_cnt[2][0] + s_cnt[3][0]);
        counts[b * 3 + 1] = (float)(s_cnt[0][1] + s_cnt[1][1] + s_cnt[2][1] + s_cnt[3][1]);
        counts[b * 3 + 2] = (float)(s_cnt[0][2] + s_cnt[1][2] + s_cnt[2][2] + s_cnt[3][2]);
    }
}

// ---------------------------------------------------------------------------
// Kernel 3: fold chunk matrices -> log-norm -> ll per seq, then reduce all
// scalars. One block x 1024 threads: seq = tid>>4, role = tid&15.
// ---------------------------------------------------------------------------
__global__ __launch_bounds__(1024) void finalize_kernel(
    const float* __restrict__ o1, const float* __restrict__ o2,
    const float* __restrict__ M1, const float* __restrict__ M2,
    const float* __restrict__ scores, const float* __restrict__ counts,
    const int* __restrict__ seqlen, float* __restrict__ out)
{
    __shared__ float s_ll1[64], s_ll2[64];
    const int tid = threadIdx.x;
    const int s = tid >> 4, r = tid & 15;
    const int base = (tid & 63) & ~15;

    if (r < 9) {
        float a[9];
#pragma unroll
        for (int k = 0; k < 9; ++k) a[k] = o2[(size_t)s * TT * 9 + k];
        for (int c = 0; c < 4; ++c) {
            const float* M = &M2[((size_t)(s * 4 + c)) * 81];
            float v[9];
#pragma unroll
            for (int k = 0; k < 9; ++k) v[k] = a[k] + M[k * 9 + r];
            float m = fmax3(fmax3(v[0], v[1], v[2]), fmax3(v[3], v[4], v[5]), fmax3(v[6], v[7], v[8]));
            float su = 0.f;
#pragma unroll
            for (int k = 0; k < 9; ++k) su += __expf(v[k] - m);
            float na = m + __logf(su);
#pragma unroll
            for (int k = 0; k < 9; ++k) a[k] = __shfl(na, base + k);
        }
        if (r == 0) {
            float m = fmax3(fmax3(a[0], a[1], a[2]), fmax3(a[3], a[4], a[5]), fmax3(a[6], a[7], a[8]));
            float su = 0.f;
#pragma unroll
            for (int k = 0; k < 9; ++k) su += __expf(a[k] - m);
            float ln = m + __logf(su);
            s_ll2[s] = (scores[s * 4 + 2] + scores[s * 4 + 3]) - ln;
        }
    } else if (r == 10 || r == 11) {
        const int j = r - 10;
        float a0 = o1[(size_t)s * TT * 2 + 0];
        float a1 = o1[(size_t)s * TT * 2 + 1];
        for (int c = 0; c < 4; ++c) {
            const float* M = &M1[((size_t)(s * 4 + c)) * 4];
            float v0 = a0 + M[0 * 2 + j], v1 = a1 + M[1 * 2 + j];
            float mm = fmaxf(v0, v1);
            float na = mm + __logf(__expf(v0 - mm) + __expf(v1 - mm));
            a0 = __shfl(na, base + 10); a1 = __shfl(na, base + 11);
        }
        if (j == 0) {
            float mm = fmaxf(a0, a1);
            float ln = mm + __logf(__expf(a0 - mm) + __expf(a1 - mm));
            s_ll1[s] = (scores[s * 4 + 0] + scores[s * 4 + 1]) - ln;
        }
    }
    __syncthreads();

    if (tid < 64) {
        float v1 = s_ll1[tid], v2 = s_ll2[tid];
        float a1 = counts[tid * 3 + 0], a2 = counts[tid * 3 + 1], ac = counts[tid * 3 + 2];
        float slf = (float)seqlen[tid];
        for (int off = 32; off; off >>= 1) {
            v1 += __shfl_down(v1, off); v2 += __shfl_down(v2, off);
            a1 += __shfl_down(a1, off); a2 += __shfl_down(a2, off);
            ac += __shfl_down(ac, off); slf += __shfl_down(slf, off);
        }
        if (tid == 0) {
            float loss1 = -v1 / 64.f;
            float loss2 = -v2 / 64.f;
            out[BB * TT + 0] = (loss1 + 8.f * loss2) / 9.f;
            out[BB * TT + 1] = a1 / slf;
            out[BB * TT + 2] = a2 / slf;
            out[BB * TT + 3] = ac / slf;
        }
    }
}

extern "C" void kernel_launch(void* const* d_in, const int* in_sizes, int n_in,
                              void* d_out, int out_size, void* d_ws, size_t ws_size,
                              hipStream_t stream) {
    (void)in_sizes; (void)n_in; (void)out_size; (void)ws_size;
    const float* x      = (const float*)d_in[0];
    const int*   label  = (const int*)d_in[1];
    const int*   seqlen = (const int*)d_in[2];
    const float* W1     = (const float*)d_in[3];
    const float* b1     = (const float*)d_in[4];
    const float* W2     = (const float*)d_in[5];
    const float* b2     = (const float*)d_in[6];
    const float* trans1 = (const float*)d_in[7];
    const float* trans2 = (const float*)d_in[8];
    float* out = (float*)d_out;
    float* ws  = (float*)d_ws;

    float* o1     = ws;                      // 65536
    float* o2     = o1 + BB * TT * 2;        // 294912
    float* M2     = o2 + BB * TT * 9;        // 64*4*81 = 20736
    float* M1     = M2 + 64 * 4 * 81;        // 1024
    float* scores = M1 + 64 * 4 * 4;         // 256
    float* counts = scores + 64 * 4;         // 192

    gemm_kernel<<<512, 256, 0, stream>>>(x, W1, b1, W2, b2, o1, o2);
    crf_kernel<<<320, 256, 0, stream>>>(o1, o2, label, seqlen, trans1, trans2,
                                        out, M1, M2, scores, counts);
    finalize_kernel<<<1, 1024, 0, stream>>>(o1, o2, M1, M2, scores, counts, seqlen, out);
}

// Round 6
// 287.170 us; speedup vs baseline: 1.5106x; 1.5106x over previous
//
#include <hip/hip_runtime.h>

#define TT 512
#define BB 64
#define DD 768
#define NEG (-1e30f)
#define GW 100   // padded LDS stride per 96-float weight segment (bank stride 4)

__device__ __forceinline__ float fmax3(float a, float b, float c) {
    return fmaxf(fmaxf(a, b), c);
}
__device__ __forceinline__ int imin3(int a, int b, int c) {
    return min(min(a, b), c);
}
__device__ __forceinline__ float rl(float x, int i) {
    return __int_as_float(__builtin_amdgcn_readlane(__float_as_int(x), i));
}
__device__ __forceinline__ float dot4(float4 a, float4 b) {
    return a.x * b.x + a.y * b.y + a.z * b.z + a.w * b.w;
}

// ---------------------------------------------------------------------------
// Kernel 1: fused skinny GEMM.
// Lane = (g = lane>>3 row-group, c = lane&7 d-segment of 96).
// Each lane: 4 rows (g, g+8, g+16, g+24 within the wave's 32 rows),
// 24 k-chunks of float4 per segment. W in LDS, stride GW=100 floats:
// 8 segments -> bank groups {0,4,...,28}, b128-aligned, conflict-free;
// one ds_read_b128 of W serves all 8 rows in the wave.
// x via 2-deep rolling register prefetch (8 float4 live). Grid 256 x 256.
// ---------------------------------------------------------------------------
__global__ __launch_bounds__(256) void gemm_kernel(
    const float* __restrict__ x,
    const float* __restrict__ W1, const float* __restrict__ b1,
    const float* __restrict__ W2, const float* __restrict__ b2,
    float* __restrict__ o1, float* __restrict__ o2)
{
    __shared__ float wseg[11 * 8 * GW];   // [(m*8+c)*GW + o], d = c*96+o
    const int tid = threadIdx.x;
    for (int i = tid; i < 11 * DD; i += 256) {
        int m = i / DD, d = i - m * DD;
        int c = d / 96, o = d - c * 96;
        float v = (m < 2) ? W1[d * 2 + m] : W2[d * 9 + (m - 2)];
        wseg[(m * 8 + c) * GW + o] = v;
    }
    __syncthreads();

    const int wave = tid >> 6, lane = tid & 63;
    const int c = lane & 7, g = lane >> 3;
    const int rbase = blockIdx.x * 128 + wave * 32 + g;

    const float4* xp[4];
#pragma unroll
    for (int j = 0; j < 4; ++j)
        xp[j] = reinterpret_cast<const float4*>(x + (size_t)(rbase + 8 * j) * DD);

    float acc[4][11];
#pragma unroll
    for (int j = 0; j < 4; ++j)
#pragma unroll
        for (int m = 0; m < 11; ++m) acc[j][m] = 0.f;

    float4 p0[4], p1[4];
#pragma unroll
    for (int j = 0; j < 4; ++j) { p0[j] = xp[j][c * 24 + 0]; p1[j] = xp[j][c * 24 + 1]; }

    for (int kk = 0; kk < 12; ++kk) {
        const int k0 = 2 * kk, k1 = 2 * kk + 1;
        float4 xa[4];
#pragma unroll
        for (int j = 0; j < 4; ++j) xa[j] = p0[j];
        if (kk < 11) {
#pragma unroll
            for (int j = 0; j < 4; ++j) p0[j] = xp[j][c * 24 + k0 + 2];
        }
#pragma unroll
        for (int m = 0; m < 11; ++m) {
            float4 wv = *reinterpret_cast<const float4*>(&wseg[(m * 8 + c) * GW + 4 * k0]);
#pragma unroll
            for (int j = 0; j < 4; ++j) acc[j][m] += dot4(xa[j], wv);
        }
        float4 xb[4];
#pragma unroll
        for (int j = 0; j < 4; ++j) xb[j] = p1[j];
        if (kk < 11) {
#pragma unroll
            for (int j = 0; j < 4; ++j) p1[j] = xp[j][c * 24 + k1 + 2];
        }
#pragma unroll
        for (int m = 0; m < 11; ++m) {
            float4 wv = *reinterpret_cast<const float4*>(&wseg[(m * 8 + c) * GW + 4 * k1]);
#pragma unroll
            for (int j = 0; j < 4; ++j) acc[j][m] += dot4(xb[j], wv);
        }
    }

    // reduce over the 8 segment-lanes (bits 0..2)
#pragma unroll
    for (int j = 0; j < 4; ++j)
#pragma unroll
        for (int m = 0; m < 11; ++m) {
            acc[j][m] += __shfl_xor(acc[j][m], 1);
            acc[j][m] += __shfl_xor(acc[j][m], 2);
            acc[j][m] += __shfl_xor(acc[j][m], 4);
        }

    if (c == 0) {
        float bb1[2] = { b1[0], b1[1] };
        float bb2[9];
#pragma unroll
        for (int m = 0; m < 9; ++m) bb2[m] = b2[m];
#pragma unroll
        for (int j = 0; j < 4; ++j) {
            const int row = rbase + 8 * j;
            o1[row * 2 + 0] = acc[j][0] + bb1[0];
            o1[row * 2 + 1] = acc[j][1] + bb1[1];
#pragma unroll
            for (int m = 0; m < 9; ++m) o2[row * 9 + m] = acc[j][m + 2] + bb2[m];
        }
    }
}

// ---------------------------------------------------------------------------
// Kernel 2: unified CRF kernel, grid = 320 blocks x 256 threads.
//  blocks 0..63  : per-seq exact Viterbi (both CRFs) + backtrace + tags +
//                  accuracy counts + unary/binary score sums.
//  blocks 64..319: (b, chunk) lse chunk transfer matrices (4 x 128 steps).
// ---------------------------------------------------------------------------
__global__ __launch_bounds__(256) void crf_kernel(
    const float* __restrict__ o1, const float* __restrict__ o2,
    const int* __restrict__ label, const int* __restrict__ seqlen,
    const float* __restrict__ trans1, const float* __restrict__ trans2,
    float* __restrict__ dout,
    float* __restrict__ M1, float* __restrict__ M2,
    float* __restrict__ scores, float* __restrict__ counts)
{
    __shared__ float s_l2[TT][9];
    __shared__ float s_l1[TT][2];
    __shared__ int   s_lab[TT];
    __shared__ float s_tr2[81];
    __shared__ float s_tr1[4];
    __shared__ unsigned char s_bp2[9][TT];    // column-major: [state][t]
    __shared__ unsigned char s_bp1[2][TT];
    __shared__ unsigned char s_path2[16][9][36];
    __shared__ unsigned char s_path1[16][2][36];
    __shared__ unsigned char s_sel2[16], s_sel1[16];
    __shared__ float s_part[2][4];
    __shared__ int s_last2, s_last1;
    __shared__ int s_cnt[4][3];

    const int tid  = threadIdx.x;
    const int wave = tid >> 6, lane = tid & 63;

    if (blockIdx.x >= 64) {
        // ================= lse chunk-matrix block =================
        const int bc  = blockIdx.x - 64;
        const int b   = bc >> 2, cch = bc & 3;
        const int sl  = seqlen[b];
        const int t0  = cch * 128 + 1;
        const int cap = (cch < 3) ? 128 : 127;
        int n = sl - t0; n = n < 0 ? 0 : (n > cap ? cap : n);

        for (int i = tid; i < cap * 9; i += 256) {
            int t = i / 9, k = i - t * 9;
            s_l2[t][k] = o2[((size_t)b * TT + t0 + t) * 9 + k];
        }
        for (int i = tid; i < cap * 2; i += 256) {
            int t = i >> 1, k = i & 1;
            s_l1[t][k] = o1[((size_t)b * TT + t0 + t) * 2 + k];
        }
        if (tid < 81) s_tr2[tid] = trans2[tid];
        if (tid >= 128 && tid < 132) s_tr1[tid - 128] = trans1[tid - 128];
        __syncthreads();

        if (wave < 2) {
            int L, i_row, jj, base2; bool active;
            if (wave == 0) {
                if (lane < 63) { active = true;  L = 9; i_row = lane / 9; jj = lane - i_row * 9; base2 = i_row * 9; }
                else           { active = false; L = 9; i_row = 0; jj = 0; base2 = 54; }
            } else {
                if (lane < 18)      { active = true;  L = 9; i_row = 7 + lane / 9; jj = lane % 9; base2 = (lane / 9) * 9; }
                else if (lane < 22) { active = true;  L = 2; i_row = (lane - 18) >> 1; jj = (lane - 18) & 1; base2 = 18 + ((lane - 18) & ~1); }
                else                { active = false; L = 2; i_row = 0; jj = 0; base2 = 18; }
            }

            float tcol[9], row[9];
#pragma unroll
            for (int k = 0; k < 9; ++k) {
                tcol[k] = (k < L) ? ((L == 9) ? s_tr2[k * 9 + jj] : s_tr1[k * 2 + jj]) : NEG;
                row[k]  = (k < L && k == i_row) ? 0.f : NEG;
            }
            const float* lp = (L == 9) ? &s_l2[0][jj] : &s_l1[0][jj];
            const int lstride = L;

            for (int tt = 0; tt < n; ++tt) {
                float l = lp[tt * lstride];
                float v[9];
#pragma unroll
                for (int k = 0; k < 9; ++k) v[k] = row[k] + tcol[k];
                float m = fmax3(fmax3(v[0], v[1], v[2]), fmax3(v[3], v[4], v[5]), fmax3(v[6], v[7], v[8]));
                float s = 0.f;
#pragma unroll
                for (int k = 0; k < 9; ++k) s += __expf(v[k] - m);
                float nv = m + __logf(s) + l;
#pragma unroll
                for (int k = 0; k < 9; ++k) {
                    float sv = __shfl(nv, base2 + (k < L ? k : 0));
                    row[k] = (k < L) ? sv : NEG;
                }
            }
            if (active) {
                if (L == 9) M2[((size_t)(b * 4 + cch)) * 81 + i_row * 9 + jj] = row[jj];
                else        M1[((size_t)(b * 4 + cch)) * 4  + i_row * 2 + jj] = row[jj];
            }
        }
        return;
    }

    // ================= per-sequence Viterbi block =================
    const int b  = blockIdx.x;
    const int sl = seqlen[b];

    // phase 0: vectorized staging + identity bp prefill (column-major)
    {
        const float4* src = (const float4*)(o2 + (size_t)b * TT * 9);
        float4* dst = (float4*)&s_l2[0][0];
        for (int i = tid; i < TT * 9 / 4; i += 256) dst[i] = src[i];
    }
    {
        const float4* src = (const float4*)(o1 + (size_t)b * TT * 2);
        float4* dst = (float4*)&s_l1[0][0];
        for (int i = tid; i < TT * 2 / 4; i += 256) dst[i] = src[i];
    }
    {
        const int4* src = (const int4*)(label + (size_t)b * TT);
        int4* dst = (int4*)s_lab;
        for (int i = tid; i < TT / 4; i += 256) dst[i] = src[i];
    }
    if (tid < 81) s_tr2[tid] = trans2[tid];
    if (tid >= 96 && tid < 100) s_tr1[tid - 96] = trans1[tid - 96];
    for (int i = tid; i < 9 * TT; i += 256) ((unsigned char*)s_bp2)[i] = (unsigned char)(i >> 9);
    for (int i = tid; i < 2 * TT; i += 256) ((unsigned char*)s_bp1)[i] = (unsigned char)(i >> 9);
    __syncthreads();

    // phase 1: forward scans + score sums
    if (wave == 0) {
        if (lane < 9) {
            const int j = lane;
            float tc0 = s_tr2[0 * 9 + j], tc1 = s_tr2[1 * 9 + j], tc2 = s_tr2[2 * 9 + j];
            float tc3 = s_tr2[3 * 9 + j], tc4 = s_tr2[4 * 9 + j], tc5 = s_tr2[5 * 9 + j];
            float tc6 = s_tr2[6 * 9 + j], tc7 = s_tr2[7 * 9 + j], tc8 = s_tr2[8 * 9 + j];
            float a0 = s_l2[0][0], a1 = s_l2[0][1], a2 = s_l2[0][2], a3 = s_l2[0][3];
            float a4 = s_l2[0][4], a5 = s_l2[0][5], a6 = s_l2[0][6], a7 = s_l2[0][7], a8 = s_l2[0][8];
            // logit prefetch, distance 4
            float lq0 = s_l2[1][j], lq1 = s_l2[2][j], lq2 = s_l2[3][j], lq3 = s_l2[4][j];
            unsigned int bpack = 0;
            for (int t = 1; t < sl; ++t) {
                int tp = t + 4; tp = tp > 511 ? 511 : tp;
                float lnew = s_l2[tp][j];
                float v0 = a0 + tc0, v1 = a1 + tc1, v2 = a2 + tc2;
                float v3 = a3 + tc3, v4 = a4 + tc4, v5 = a5 + tc5;
                float v6 = a6 + tc6, v7 = a7 + tc7, v8 = a8 + tc8;
                float m = fmax3(fmax3(v0, v1, v2), fmax3(v3, v4, v5), fmax3(v6, v7, v8));
                float nj = m + lq0;
                float n0 = rl(nj, 0), n1 = rl(nj, 1), n2 = rl(nj, 2);
                float n3 = rl(nj, 3), n4 = rl(nj, 4), n5 = rl(nj, 5);
                float n6 = rl(nj, 6), n7 = rl(nj, 7), n8 = rl(nj, 8);
                int c0 = (v0 == m) ? 0 : 15, c1 = (v1 == m) ? 1 : 15, c2 = (v2 == m) ? 2 : 15;
                int c3 = (v3 == m) ? 3 : 15, c4 = (v4 == m) ? 4 : 15, c5 = (v5 == m) ? 5 : 15;
                int c6 = (v6 == m) ? 6 : 15, c7 = (v7 == m) ? 7 : 15, c8 = (v8 == m) ? 8 : 15;
                int bi = imin3(imin3(c0, c1, c2), imin3(c3, c4, c5), imin3(c6, c7, c8));
                bpack |= (unsigned int)bi << ((t & 3) * 8);
                if ((t & 3) == 3) {
                    *(unsigned int*)&s_bp2[j][t - 3] = bpack;   // bytes t-3..t, all < sl
                    bpack = 0;
                }
                a0 = n0; a1 = n1; a2 = n2; a3 = n3; a4 = n4; a5 = n5; a6 = n6; a7 = n7; a8 = n8;
                lq0 = lq1; lq1 = lq2; lq2 = lq3; lq3 = lnew;
            }
            // tail: pending bytes (byte-writes so identity beyond sl survives)
            if (((sl - 1) & 3) != 3) {
                int Gp = (sl - 1) & ~3; if (Gp < 1) Gp = 1;
                for (int tt = Gp; tt < sl; ++tt)
                    s_bp2[j][tt] = (unsigned char)((bpack >> ((tt & 3) * 8)) & 0xff);
            }
            if (lane == 0) {
                float m = fmax3(fmax3(a0, a1, a2), fmax3(a3, a4, a5), fmax3(a6, a7, a8));
                int c0 = (a0 == m) ? 0 : 15, c1 = (a1 == m) ? 1 : 15, c2 = (a2 == m) ? 2 : 15;
                int c3 = (a3 == m) ? 3 : 15, c4 = (a4 == m) ? 4 : 15, c5 = (a5 == m) ? 5 : 15;
                int c6 = (a6 == m) ? 6 : 15, c7 = (a7 == m) ? 7 : 15, c8 = (a8 == m) ? 8 : 15;
                s_last2 = imin3(imin3(c0, c1, c2), imin3(c3, c4, c5), imin3(c6, c7, c8));
            }
        }
    } else if (wave == 1) {
        if (lane == 0) {
            const float t00 = s_tr1[0], t01 = s_tr1[1], t10 = s_tr1[2], t11 = s_tr1[3];
            float a0v = s_l1[0][0], a1v = s_l1[0][1];
            float2 lA = *(const float2*)&s_l1[1][0];
            float2 lB = *(const float2*)&s_l1[2][0];
            float2 lC = *(const float2*)&s_l1[3][0];
            float2 lD = *(const float2*)&s_l1[4][0];
            unsigned int pk0 = 0, pk1 = 0;
            for (int t = 1; t < sl; ++t) {
                int tp = t + 4; tp = tp > 511 ? 511 : tp;
                float2 lw = *(const float2*)&s_l1[tp][0];
                float x0 = a0v + t00, y0 = a1v + t10;
                int bp0 = (y0 > x0) ? 1 : 0;
                float n0 = fmaxf(x0, y0) + lA.x;
                float x1 = a0v + t01, y1 = a1v + t11;
                int bp1v = (y1 > x1) ? 1 : 0;
                float n1 = fmaxf(x1, y1) + lA.y;
                pk0 |= (unsigned int)bp0 << ((t & 3) * 8);
                pk1 |= (unsigned int)bp1v << ((t & 3) * 8);
                if ((t & 3) == 3) {
                    *(unsigned int*)&s_bp1[0][t - 3] = pk0;
                    *(unsigned int*)&s_bp1[1][t - 3] = pk1;
                    pk0 = 0; pk1 = 0;
                }
                a0v = n0; a1v = n1; lA = lB; lB = lC; lC = lD; lD = lw;
            }
            if (((sl - 1) & 3) != 3) {
                int Gp = (sl - 1) & ~3; if (Gp < 1) Gp = 1;
                for (int tt = Gp; tt < sl; ++tt) {
                    s_bp1[0][tt] = (unsigned char)((pk0 >> ((tt & 3) * 8)) & 0xff);
                    s_bp1[1][tt] = (unsigned char)((pk1 >> ((tt & 3) * 8)) & 0xff);
                }
            }
            s_last1 = (a1v > a0v) ? 1 : 0;
        }
    } else {
        const int t0i = tid - 128;
        float u1 = 0.f, bs1 = 0.f, u2 = 0.f, bs2 = 0.f;
        for (int t = t0i; t < sl; t += 128) {
            int lb = s_lab[t]; int lb1 = lb > 0 ? 1 : 0;
            u1 += s_l1[t][lb1];
            u2 += s_l2[t][lb];
            if (t >= 1) {
                int lp = s_lab[t - 1]; int lp1 = lp > 0 ? 1 : 0;
                bs1 += s_tr1[lp1 * 2 + lb1];
                bs2 += s_tr2[lp * 9 + lb];
            }
        }
        for (int off = 32; off; off >>= 1) {
            u1 += __shfl_down(u1, off); bs1 += __shfl_down(bs1, off);
            u2 += __shfl_down(u2, off); bs2 += __shfl_down(bs2, off);
        }
        if (lane == 0) {
            s_part[wave - 2][0] = u1; s_part[wave - 2][1] = bs1;
            s_part[wave - 2][2] = u2; s_part[wave - 2][3] = bs2;
        }
    }
    __syncthreads();

    // phase 2: chunk-parallel backtraces (16 chunks x 32 steps, exact)
    if (tid < 144) {
        int cch = tid / 9, e = tid - cch * 9;
        int pe = (cch < 15) ? (cch + 1) * 32 : 511;
        int tag = e;
        for (int t = pe; t > cch * 32; --t) {
            tag = s_bp2[tag][t];
            s_path2[cch][e][t - 1 - cch * 32] = (unsigned char)tag;
        }
    } else if (tid >= 160 && tid < 192) {
        int k = tid - 160, cch = k >> 1, e = k & 1;
        int pe = (cch < 15) ? (cch + 1) * 32 : 511;
        int tag = e;
        for (int t = pe; t > cch * 32; --t) {
            tag = s_bp1[tag][t];
            s_path1[cch][e][t - 1 - cch * 32] = (unsigned char)tag;
        }
    } else if (tid >= 224 && tid < 228) {
        int k = tid - 224;
        scores[b * 4 + k] = s_part[0][k] + s_part[1][k];
    }
    __syncthreads();

    // phase 3: boundary resolve
    if (tid == 0) {
        int cur = s_last2;
        for (int c = 15; c >= 0; --c) { s_sel2[c] = (unsigned char)cur; cur = s_path2[c][cur][0]; }
    } else if (tid == 1) {
        int cur = s_last1;
        for (int c = 15; c >= 0; --c) { s_sel1[c] = (unsigned char)cur; cur = s_path1[c][cur][0]; }
    }
    __syncthreads();

    // phase 4: assemble tags + accuracy counts
    {
        int c1 = 0, c2 = 0, cc = 0;
        for (int p = tid; p < TT; p += 256) {
            int ch = p >> 5;
            int v2 = (p == 511) ? s_last2 : (int)s_path2[ch][s_sel2[ch]][p & 31];
            int v1 = (p == 511) ? s_last1 : (int)s_path1[ch][s_sel1[ch]][p & 31];
            int comb = (v1 == 0) ? 0 : v2;
            dout[(size_t)b * TT + p] = (float)comb;
            if (p < sl) {
                int lb = s_lab[p]; int lb1 = lb > 0 ? 1 : 0;
                c1 += (v1 == lb1); c2 += (v2 == lb); cc += (comb == lb);
            }
        }
        for (int off = 32; off; off >>= 1) {
            c1 += __shfl_down(c1, off); c2 += __shfl_down(c2, off); cc += __shfl_down(cc, off);
        }
        if (lane == 0) { s_cnt[wave][0] = c1; s_cnt[wave][1] = c2; s_cnt[wave][2] = cc; }
    }
    __syncthreads();
    if (tid == 0) {
        counts[b * 3 + 0] = (float)(s_cnt[0][0] + s_cnt[1][0] + s_cnt[2][0] + s_cnt[3][0]);
        counts[b * 3 + 1] = (float)(s_cnt[0][1] + s_cnt[1][1] + s_cnt[2][1] + s_cnt[3][1]);
        counts[b * 3 + 2] = (float)(s_cnt[0][2] + s_cnt[1][2] + s_cnt[2][2] + s_cnt[3][2]);
    }
}

// ---------------------------------------------------------------------------
// Kernel 3: fold chunk matrices -> log-norm -> ll per seq, then reduce all
// scalars. One block x 1024 threads: seq = tid>>4, role = tid&15.
// ---------------------------------------------------------------------------
__global__ __launch_bounds__(1024) void finalize_kernel(
    const float* __restrict__ o1, const float* __restrict__ o2,
    const float* __restrict__ M1, const float* __restrict__ M2,
    const float* __restrict__ scores, const float* __restrict__ counts,
    const int* __restrict__ seqlen, float* __restrict__ out)
{
    __shared__ float s_ll1[64], s_ll2[64];
    const int tid = threadIdx.x;
    const int s = tid >> 4, r = tid & 15;
    const int base = (tid & 63) & ~15;

    if (r < 9) {
        float a[9];
#pragma unroll
        for (int k = 0; k < 9; ++k) a[k] = o2[(size_t)s * TT * 9 + k];
        for (int c = 0; c < 4; ++c) {
            const float* M = &M2[((size_t)(s * 4 + c)) * 81];
            float v[9];
#pragma unroll
            for (int k = 0; k < 9; ++k) v[k] = a[k] + M[k * 9 + r];
            float m = fmax3(fmax3(v[0], v[1], v[2]), fmax3(v[3], v[4], v[5]), fmax3(v[6], v[7], v[8]));
            float su = 0.f;
#pragma unroll
            for (int k = 0; k < 9; ++k) su += __expf(v[k] - m);
            float na = m + __logf(su);
#pragma unroll
            for (int k = 0; k < 9; ++k) a[k] = __shfl(na, base + k);
        }
        if (r == 0) {
            float m = fmax3(fmax3(a[0], a[1], a[2]), fmax3(a[3], a[4], a[5]), fmax3(a[6], a[7], a[8]));
            float su = 0.f;
#pragma unroll
            for (int k = 0; k < 9; ++k) su += __expf(a[k] - m);
            float ln = m + __logf(su);
            s_ll2[s] = (scores[s * 4 + 2] + scores[s * 4 + 3]) - ln;
        }
    } else if (r == 10 || r == 11) {
        const int j = r - 10;
        float a0 = o1[(size_t)s * TT * 2 + 0];
        float a1 = o1[(size_t)s * TT * 2 + 1];
        for (int c = 0; c < 4; ++c) {
            const float* M = &M1[((size_t)(s * 4 + c)) * 4];
            float v0 = a0 + M[0 * 2 + j], v1 = a1 + M[1 * 2 + j];
            float mm = fmaxf(v0, v1);
            float na = mm + __logf(__expf(v0 - mm) + __expf(v1 - mm));
            a0 = __shfl(na, base + 10); a1 = __shfl(na, base + 11);
        }
        if (j == 0) {
            float mm = fmaxf(a0, a1);
            float ln = mm + __logf(__expf(a0 - mm) + __expf(a1 - mm));
            s_ll1[s] = (scores[s * 4 + 0] + scores[s * 4 + 1]) - ln;
        }
    }
    __syncthreads();

    if (tid < 64) {
        float v1 = s_ll1[tid], v2 = s_ll2[tid];
        float a1 = counts[tid * 3 + 0], a2 = counts[tid * 3 + 1], ac = counts[tid * 3 + 2];
        float slf = (float)seqlen[tid];
        for (int off = 32; off; off >>= 1) {
            v1 += __shfl_down(v1, off); v2 += __shfl_down(v2, off);
            a1 += __shfl_down(a1, off); a2 += __shfl_down(a2, off);
            ac += __shfl_down(ac, off); slf += __shfl_down(slf, off);
        }
        if (tid == 0) {
            float loss1 = -v1 / 64.f;
            float loss2 = -v2 / 64.f;
            out[BB * TT + 0] = (loss1 + 8.f * loss2) / 9.f;
            out[BB * TT + 1] = a1 / slf;
            out[BB * TT + 2] = a2 / slf;
            out[BB * TT + 3] = ac / slf;
        }
    }
}

extern "C" void kernel_launch(void* const* d_in, const int* in_sizes, int n_in,
                              void* d_out, int out_size, void* d_ws, size_t ws_size,
                              hipStream_t stream) {
    (void)in_sizes; (void)n_in; (void)out_size; (void)ws_size;
    const float* x      = (const float*)d_in[0];
    const int*   label  = (const int*)d_in[1];
    const int*   seqlen = (const int*)d_in[2];
    const float* W1     = (const float*)d_in[3];
    const float* b1     = (const float*)d_in[4];
    const float* W2     = (const float*)d_in[5];
    const float* b2     = (const float*)d_in[6];
    const float* trans1 = (const float*)d_in[7];
    const float* trans2 = (const float*)d_in[8];
    float* out = (float*)d_out;
    float* ws  = (float*)d_ws;

    float* o1     = ws;                      // 65536
    float* o2     = o1 + BB * TT * 2;        // 294912
    float* M2     = o2 + BB * TT * 9;        // 64*4*81 = 20736
    float* M1     = M2 + 64 * 4 * 81;        // 1024
    float* scores = M1 + 64 * 4 * 4;         // 256
    float* counts = scores + 64 * 4;         // 192

    gemm_kernel<<<256, 256, 0, stream>>>(x, W1, b1, W2, b2, o1, o2);
    crf_kernel<<<320, 256, 0, stream>>>(o1, o2, label, seqlen, trans1, trans2,
                                        out, M1, M2, scores, counts);
    finalize_kernel<<<1, 1024, 0, stream>>>(o1, o2, M1, M2, scores, counts, seqlen, out);
}